// Round 6
// baseline (603.899 us; speedup 1.0000x reference)
//
#include <hip/hip_runtime.h>

// GCN: 2x GCNConv(+self-loop sym-norm) + ReLU, global mean pool, linear head.
// N=100000, E=1600000, G=100, D_IN=3, H=128, OUT=10.
//
// R5->R6: (1) agg2pool: group-per-node gather (16 lanes own a node, 4 nodes
// per wave in parallel) -> no shfl reductions at all; 2-deep pipelined row
// loads. (2) h1 stored as fp8 e4m3 (128B/row): halves gather bytes, HW
// cvt_pk_f32_fp8 + packed adds halve unpack VALU. (3) layer-1 aggregation
// folded into the CSR fill as 3 fp32 L2-atomics/edge; layer-1 GEMM is dense.
//
// All kernels static + gcn364_ prefix (cross-.so symbol collisions caused the
// round-1 silent failure). Runtime dtype probe handles bf16/fp32 harness mode.

#define DIN 3
#define H 128
#define OUTF 10
#define NWEIGHT (384 + 128 + 16384 + 128 + 1280 + 10)  // W1,b1,W2,b2,Wl,bl

typedef float gcn364_f2 __attribute__((ext_vector_type(2)));

__device__ __forceinline__ float gcn364_bf2f(unsigned short u) {
    return __uint_as_float(((unsigned int)u) << 16);
}
__device__ __forceinline__ unsigned short gcn364_f2bf(float f) {
    unsigned int u = __float_as_uint(f);
    u += 0x7FFFu + ((u >> 16) & 1u);   // round-to-nearest-even
    return (unsigned short)(u >> 16);
}

#if __has_builtin(__builtin_amdgcn_cvt_pk_f32_fp8) && __has_builtin(__builtin_amdgcn_cvt_pk_fp8_f32)
#define GCN364_HWFP8 1
#endif

#ifndef GCN364_HWFP8
// software e4m3fn fallback (correctness only; HW path expected on gfx950)
__device__ __forceinline__ float gcn364_dec1(unsigned v) {
    unsigned e = (v >> 3) & 15u, m = v & 7u;
    float mag = e ? ldexpf((float)(8 + m), (int)e - 10) : ldexpf((float)m, -9);
    return (v & 0x80u) ? -mag : mag;
}
__device__ __forceinline__ unsigned gcn364_enc1(float f) {
    float a = fabsf(f);
    unsigned s = (__float_as_uint(f) >> 31) << 7;
    if (!(a > 0.f)) return s;
    if (a >= 448.f) return s | 0x7e;
    int ex; float fr = frexpf(a, &ex);   // a = fr*2^ex, fr in [0.5,1)
    int e = ex + 6;
    if (e <= 0) {
        unsigned m = (unsigned)(a * 512.f + 0.5f);
        if (m >= 8) return s | 0x08;
        return s | m;
    }
    unsigned m = (unsigned)(fr * 16.f - 8.f + 0.5f);
    if (m >= 8) { m = 0; e++; if (e > 15) return s | 0x7e; }
    return s | ((unsigned)e << 3) | m;
}
#endif

template<bool HI>
__device__ __forceinline__ gcn364_f2 gcn364_dec8(unsigned int u) {
#ifdef GCN364_HWFP8
    return __builtin_amdgcn_cvt_pk_f32_fp8((int)u, HI);
#else
    unsigned b = HI ? (u >> 16) : (u & 0xffffu);
    gcn364_f2 r;
    r.x = gcn364_dec1(b & 0xffu);
    r.y = gcn364_dec1((b >> 8) & 0xffu);
    return r;
#endif
}

template<bool HI>
__device__ __forceinline__ unsigned int gcn364_enc8(float f0, float f1, unsigned int old) {
#ifdef GCN364_HWFP8
    return (unsigned int)__builtin_amdgcn_cvt_pk_fp8_f32(f0, f1, (int)old, HI);
#else
    unsigned p = gcn364_enc1(f0) | (gcn364_enc1(f1) << 8);
    return HI ? ((old & 0x0000ffffu) | (p << 16)) : ((old & 0xffff0000u) | p);
#endif
}

// ---- dtype probe: flag=1 if x is fp32, flag=0 if bf16 ----
static __global__ void gcn364_detect(const unsigned short* __restrict__ xraw,
                                     int* __restrict__ flag) {
    __shared__ int cnt;
    if (threadIdx.x == 0) cnt = 0;
    __syncthreads();
    unsigned short u = xraw[threadIdx.x];
    int e = (u >> 7) & 0xFF;
    int outlier = (e < 100 || e > 140) ? 1 : 0;
    atomicAdd(&cnt, outlier);
    __syncthreads();
    if (threadIdx.x == 0) *flag = (cnt > 32) ? 1 : 0;
}

// ---- convert float inputs to fp32 region + int degree count (merged) ----
static __global__ void gcn364_convdeg(const void* __restrict__ x,
                                      const void* __restrict__ W1, const void* __restrict__ b1,
                                      const void* __restrict__ W2, const void* __restrict__ b2,
                                      const void* __restrict__ Wl, const void* __restrict__ bl,
                                      const int* __restrict__ flag,
                                      float* __restrict__ dstf,
                                      const int* __restrict__ edst, int* __restrict__ deg,
                                      int N, int E) {
    int i = blockIdx.x * blockDim.x + threadIdx.x;
    if (i < E) atomicAdd(&deg[edst[i]], 1);
    int total = DIN * N + NWEIGHT;
    if (i >= total) return;
    const void* srcp; int j = i;
    if (j < DIN * N) { srcp = x; }
    else {
        j -= DIN * N;
        if      (j < 384)                       { srcp = W1; }
        else if ((j -= 384)   < 128)            { srcp = b1; }
        else if ((j -= 128)   < 16384)          { srcp = W2; }
        else if ((j -= 16384) < 128)            { srcp = b2; }
        else if ((j -= 128)   < 1280)           { srcp = Wl; }
        else    { j -= 1280;                      srcp = bl; }
    }
    float v = (*flag) ? ((const float*)srcp)[j]
                      : gcn364_bf2f(((const unsigned short*)srcp)[j]);
    dstf[i] = v;
}

// ---- exclusive scan of deg[N] -> off[N], 1024 items/block ----
static __global__ void gcn364_scan1(const int* __restrict__ deg, int* __restrict__ off,
                                    int* __restrict__ partials, int N) {
    __shared__ int sh[256];
    int t = threadIdx.x;
    int base = blockIdx.x * 1024 + t * 4;
    int v0 = (base + 0 < N) ? deg[base + 0] : 0;
    int v1 = (base + 1 < N) ? deg[base + 1] : 0;
    int v2 = (base + 2 < N) ? deg[base + 2] : 0;
    int v3 = (base + 3 < N) ? deg[base + 3] : 0;
    int s = v0 + v1 + v2 + v3;
    sh[t] = s;
    __syncthreads();
    for (int d = 1; d < 256; d <<= 1) {
        int val = (t >= d) ? sh[t - d] : 0;
        __syncthreads();
        sh[t] += val;
        __syncthreads();
    }
    int excl = sh[t] - s;
    int run = excl;
    if (base + 0 < N) off[base + 0] = run; run += v0;
    if (base + 1 < N) off[base + 1] = run; run += v1;
    if (base + 2 < N) off[base + 2] = run; run += v2;
    if (base + 3 < N) off[base + 3] = run;
    if (t == 255) partials[blockIdx.x] = sh[255];
}

// block 0: scan of partials; block 1: nodes-per-graph via binary search
static __global__ void gcn364_scan2cnt(int* __restrict__ partials, int nb,
                                       const int* __restrict__ batch,
                                       float* __restrict__ cnt, int N, int G) {
    if (blockIdx.x == 0) {
        __shared__ int sh[256];
        int t = threadIdx.x;
        int v = (t < nb) ? partials[t] : 0;
        sh[t] = v;
        __syncthreads();
        for (int d = 1; d < 256; d <<= 1) {
            int val = (t >= d) ? sh[t - d] : 0;
            __syncthreads();
            sh[t] += val;
            __syncthreads();
        }
        if (t < nb) partials[t] = sh[t] - v;   // exclusive
    } else {
        for (int g = threadIdx.x; g < G; g += blockDim.x) {
            int lo = 0, hi = N;
            while (lo < hi) { int m = (lo + hi) >> 1; if (batch[m] < g) lo = m + 1; else hi = m; }
            int a = lo;
            lo = 0; hi = N;
            while (lo < hi) { int m = (lo + hi) >> 1; if (batch[m] < g + 1) lo = m + 1; else hi = m; }
            cnt[g] = (float)(lo - a);
        }
    }
}

// scan finalize + dinvs + in-place pre-scale of xf by dinvs
static __global__ void gcn364_scan3(int* __restrict__ off, const int* __restrict__ partials,
                                    const int* __restrict__ deg, float* __restrict__ dinvs,
                                    float* __restrict__ xf, int N) {
    int i = blockIdx.x * blockDim.x + threadIdx.x;
    if (i >= N) return;
    off[i] += partials[i >> 10];
    float di = rsqrtf((float)deg[i] + 1.0f);
    dinvs[i] = di;
    xf[i * DIN + 0] *= di;
    xf[i * DIN + 1] *= di;
    xf[i * DIN + 2] *= di;
}

// CSR fill + layer-1 aggregation: place edge in bucket AND accumulate the
// (pre-scaled) 3-feature source vector into aggX[dst] via L2 atomics.
// off[] doubles as cursor; afterwards off[i] == end offset of node i.
static __global__ void gcn364_fillagg(const int* __restrict__ src, const int* __restrict__ dst,
                                      int* __restrict__ off, int* __restrict__ esrc,
                                      const float* __restrict__ xf, float* __restrict__ aggX,
                                      int E) {
    int e = blockIdx.x * blockDim.x + threadIdx.x;
    if (e >= E) return;
    int s = src[e], d = dst[e];
    int p = atomicAdd(&off[d], 1);
    esrc[p] = s;
    atomicAdd(&aggX[d * DIN + 0], xf[s * DIN + 0]);
    atomicAdd(&aggX[d * DIN + 1], xf[s * DIN + 1]);
    atomicAdd(&aggX[d * DIN + 2], xf[s * DIN + 2]);
}

// Dense layer 1: h1q = fp8(dinvs * relu((di*(aggX+xf)) @ W1 + b1)).
// 16 threads per node, 8 features each, coalesced 8B stores.
static __global__ void gcn364_layer1(const float* __restrict__ xf,
                                     const float* __restrict__ aggX,
                                     const float* __restrict__ dinvs,
                                     const float* __restrict__ w1f,
                                     const float* __restrict__ b1f,
                                     uint2* __restrict__ h1q, int N) {
    int gid = blockIdx.x * blockDim.x + threadIdx.x;
    int i = gid >> 4;
    int sub = gid & 15;
    if (i >= N) return;
    float di = dinvs[i];
    float v0 = di * (aggX[i * DIN + 0] + xf[i * DIN + 0]);
    float v1 = di * (aggX[i * DIN + 1] + xf[i * DIN + 1]);
    float v2 = di * (aggX[i * DIN + 2] + xf[i * DIN + 2]);
    float r[8];
    #pragma unroll
    for (int q = 0; q < 8; q++) {
        int f = sub * 8 + q;
        r[q] = di * fmaxf(v0 * w1f[f] + v1 * w1f[H + f] + v2 * w1f[2 * H + f] + b1f[f], 0.f);
    }
    unsigned int lo = 0, hi = 0;
    lo = gcn364_enc8<false>(r[0], r[1], lo);
    lo = gcn364_enc8<true >(r[2], r[3], lo);
    hi = gcn364_enc8<false>(r[4], r[5], hi);
    hi = gcn364_enc8<true >(r[6], r[7], hi);
    uint2 o; o.x = lo; o.y = hi;
    h1q[(size_t)i * 16 + sub] = o;
}

// Fused layer-2 CSR aggregation + GEMM + relu + mean-pool.
// Block = 256 thr = 4 waves; MPB=16 nodes/block. Phase A: each 16-lane group
// owns ONE node (4 nodes per wave in parallel) -> no reductions/shuffles.
// Rows are fp8 (128B): lane loads uint2, HW cvt_pk_f32_fp8 + packed adds.
// 2-deep pipelined row loads for MLP. Phase B: 8-acc GEMM, float4 LDS reads,
// grouped atomics into pooled (batch sorted).
#define MPB 16
static __global__ void gcn364_agg2pool(const int* __restrict__ esrc,
                                       const int* __restrict__ endoff,
                                       const uint2* __restrict__ h1q,
                                       const float* __restrict__ dinvs,
                                       const float* __restrict__ w2f,
                                       const float* __restrict__ b2f,
                                       const int* __restrict__ batch,
                                       float* __restrict__ pooled, int N) {
    __shared__ float vsh[MPB][H];
    int i0 = blockIdx.x * MPB;
    int wave = threadIdx.x >> 6;
    int lane = threadIdx.x & 63;
    int grp = lane >> 4;
    int sub = lane & 15;
    int node = wave * 4 + grp;
    int i = i0 + node;

    gcn364_f2 a01 = {0.f, 0.f}, a23 = {0.f, 0.f}, a45 = {0.f, 0.f}, a67 = {0.f, 0.f};
    if (i < N) {
        int p0 = (i == 0) ? 0 : endoff[i - 1];
        int p1 = endoff[i];
        int p = p0;
        for (; p + 2 <= p1; p += 2) {
            int s0 = esrc[p];
            int s1 = esrc[p + 1];
            uint2 u0 = h1q[(size_t)s0 * 16 + sub];
            uint2 u1 = h1q[(size_t)s1 * 16 + sub];
            a01 += gcn364_dec8<false>(u0.x); a23 += gcn364_dec8<true>(u0.x);
            a45 += gcn364_dec8<false>(u0.y); a67 += gcn364_dec8<true>(u0.y);
            a01 += gcn364_dec8<false>(u1.x); a23 += gcn364_dec8<true>(u1.x);
            a45 += gcn364_dec8<false>(u1.y); a67 += gcn364_dec8<true>(u1.y);
        }
        if (p < p1) {
            int s0 = esrc[p];
            uint2 u0 = h1q[(size_t)s0 * 16 + sub];
            a01 += gcn364_dec8<false>(u0.x); a23 += gcn364_dec8<true>(u0.x);
            a45 += gcn364_dec8<false>(u0.y); a67 += gcn364_dec8<true>(u0.y);
        }
        {   // self-loop
            uint2 u0 = h1q[(size_t)i * 16 + sub];
            a01 += gcn364_dec8<false>(u0.x); a23 += gcn364_dec8<true>(u0.x);
            a45 += gcn364_dec8<false>(u0.y); a67 += gcn364_dec8<true>(u0.y);
        }
        float di = dinvs[i];
        a01 *= di; a23 *= di; a45 *= di; a67 *= di;
        *(float4*)&vsh[node][sub * 8 + 0] = make_float4(a01.x, a01.y, a23.x, a23.y);
        *(float4*)&vsh[node][sub * 8 + 4] = make_float4(a45.x, a45.y, a67.x, a67.y);
    }
    __syncthreads();

    int f = threadIdx.x & (H - 1);
    int half = threadIdx.x >> 7;
    float acc2[8] = {0.f, 0.f, 0.f, 0.f, 0.f, 0.f, 0.f, 0.f};
    for (int k4 = 0; k4 < H / 4; k4++) {
        float w0 = w2f[(k4 * 4 + 0) * H + f];
        float w1 = w2f[(k4 * 4 + 1) * H + f];
        float w2 = w2f[(k4 * 4 + 2) * H + f];
        float w3 = w2f[(k4 * 4 + 3) * H + f];
        #pragma unroll
        for (int n = 0; n < 8; n++) {
            float4 v = *(const float4*)&vsh[2 * n + half][k4 * 4];
            acc2[n] += v.x * w0 + v.y * w1 + v.z * w2 + v.w * w3;
        }
    }
    float bb = b2f[f];

    float sum = 0.0f;
    int curg = -1;
    #pragma unroll
    for (int j = 0; j < 8; j++) {
        int ii = i0 + half + 2 * j;
        if (ii >= N) continue;
        float val = fmaxf(acc2[j] + bb, 0.0f);
        int g = batch[ii];
        if (g != curg) {
            if (curg >= 0) atomicAdd(&pooled[curg * H + f], sum);
            curg = g;
            sum = 0.0f;
        }
        sum += val;
    }
    if (curg >= 0) atomicAdd(&pooled[curg * H + f], sum);
}

// out[g] = (pooled[g]/max(cnt,1)) @ Wl + bl  -> detected dtype
static __global__ void gcn364_final(const float* __restrict__ pooled,
                                    const float* __restrict__ cnt,
                                    const float* __restrict__ wlf,
                                    const float* __restrict__ blf,
                                    const int* __restrict__ flag,
                                    void* __restrict__ out, int G) {
    int g = blockIdx.x;
    int o = threadIdx.x;
    if (g >= G || o >= OUTF) return;
    float inv = 1.0f / fmaxf(cnt[g], 1.0f);
    float acc = 0.0f;
    for (int k = 0; k < H; k++)
        acc += pooled[g * H + k] * wlf[k * OUTF + o];
    float v = acc * inv + blf[o];
    if (*flag) ((float*)out)[g * OUTF + o] = v;
    else       ((unsigned short*)out)[g * OUTF + o] = gcn364_f2bf(v);
}

extern "C" void kernel_launch(void* const* d_in, const int* in_sizes, int n_in,
                              void* d_out, int out_size, void* d_ws, size_t ws_size,
                              hipStream_t stream) {
    const void* x  = d_in[0];
    const int* edge_index = (const int*)d_in[1];
    const int* batch      = (const int*)d_in[2];
    const void* W1 = d_in[3];
    const void* b1 = d_in[4];
    const void* W2 = d_in[5];
    const void* b2 = d_in[6];
    const void* Wl = d_in[7];
    const void* bl = d_in[8];

    const int N = in_sizes[0] / DIN;
    const int E = in_sizes[1] / 2;
    const int G = out_size / OUTF;
    const int* src = edge_index;
    const int* dst = edge_index + E;
    const int NB = (N + 1023) / 1024;   // scan blocks (must be <= 256)

    // ---- workspace layout (4B units); deg+pooled+aggX zeroed (contiguous) ----
    char* wsb = (char*)d_ws;
    int*   deg      = (int*)wsb;                                  // N      (zeroed)
    float* pooled   = (float*)(deg + N);                          // G*H    (zeroed)
    float* aggX     = pooled + (size_t)G * H;                     // 3N     (zeroed)
    int*   off      = (int*)(aggX + (size_t)DIN * N);             // N
    int*   partials = off + N;                                    // 256
    float* cnt      = (float*)(partials + 256);                   // G
    float* dinvs    = cnt + G;                                    // N
    float* xf       = dinvs + N;                                  // 3N
    float* wf       = xf + (size_t)DIN * N;                       // NWEIGHT
    int*   flag     = (int*)(wf + NWEIGHT);                       // 1
    int*   esrc     = flag + 1;                                   // E
    size_t h1off = (((size_t)(esrc + E) - (size_t)wsb) + 15) & ~(size_t)15;
    uint2* h1q = (uint2*)(wsb + h1off);                           // N*16 uint2 (fp8 rows)

    float* w1f = wf;
    float* b1f = w1f + 384;
    float* w2f = b1f + 128;
    float* b2f = w2f + 16384;
    float* wlf = b2f + 128;
    float* blf = wlf + 1280;

    hipMemsetAsync(d_ws, 0, ((size_t)N + (size_t)G * H + (size_t)DIN * N) * 4, stream);

    gcn364_detect<<<1, 256, 0, stream>>>((const unsigned short*)x, flag);
    {
        int total = DIN * N + NWEIGHT;
        int gmax = (E > total) ? E : total;
        gcn364_convdeg<<<(gmax + 255) / 256, 256, 0, stream>>>(
            x, W1, b1, W2, b2, Wl, bl, flag, xf, dst, deg, N, E);
    }
    gcn364_scan1<<<NB, 256, 0, stream>>>(deg, off, partials, N);
    gcn364_scan2cnt<<<2, 256, 0, stream>>>(partials, NB, batch, cnt, N, G);
    gcn364_scan3<<<(N + 255) / 256, 256, 0, stream>>>(off, partials, deg, dinvs, xf, N);
    gcn364_fillagg<<<(E + 255) / 256, 256, 0, stream>>>(src, dst, off, esrc, xf, aggX, E);
    gcn364_layer1<<<((size_t)N * 16 + 255) / 256, 256, 0, stream>>>(
        xf, aggX, dinvs, w1f, b1f, h1q, N);
    gcn364_agg2pool<<<(N + MPB - 1) / MPB, 256, 0, stream>>>(
        esrc, off, h1q, dinvs, w2f, b2f, batch, pooled, N);
    gcn364_final<<<G, 64, 0, stream>>>(pooled, cnt, wlf, blf, flag, d_out, G);
}

// Round 7
// 426.749 us; speedup vs baseline: 1.4151x; 1.4151x over previous
//
#include <hip/hip_runtime.h>

// GCN: 2x GCNConv(+self-loop sym-norm) + ReLU, global mean pool, linear head.
// N=100000, E=1600000, G=100, D_IN=3, H=128, OUT=10.
//
// R6->R7: revert the fillagg regression (per-edge fp32 atomics into 12B aggX
// rows caused 255MB of HBM RMW write-backs, 304us @ VALUBusy 0.2%). Layer-1
// agg+GEMM go back to the R5 l1fused structure (16 lanes/node CSR gather,
// shfl_xor reduce, per-lane 8-feature GEMM) now emitting fp8 rows. Keep R6's
// fp8 h1 storage + group-per-node agg2pool (validated: agg2pool left top-5).
//
// All kernels static + gcn364_ prefix (cross-.so symbol collisions caused the
// round-1 silent failure). Runtime dtype probe handles bf16/fp32 harness mode.

#define DIN 3
#define H 128
#define OUTF 10
#define NWEIGHT (384 + 128 + 16384 + 128 + 1280 + 10)  // W1,b1,W2,b2,Wl,bl

typedef float gcn364_f2 __attribute__((ext_vector_type(2)));

__device__ __forceinline__ float gcn364_bf2f(unsigned short u) {
    return __uint_as_float(((unsigned int)u) << 16);
}
__device__ __forceinline__ unsigned short gcn364_f2bf(float f) {
    unsigned int u = __float_as_uint(f);
    u += 0x7FFFu + ((u >> 16) & 1u);   // round-to-nearest-even
    return (unsigned short)(u >> 16);
}

#if __has_builtin(__builtin_amdgcn_cvt_pk_f32_fp8) && __has_builtin(__builtin_amdgcn_cvt_pk_fp8_f32)
#define GCN364_HWFP8 1
#endif

#ifndef GCN364_HWFP8
// software e4m3fn fallback (correctness only; HW path expected on gfx950)
__device__ __forceinline__ float gcn364_dec1(unsigned v) {
    unsigned e = (v >> 3) & 15u, m = v & 7u;
    float mag = e ? ldexpf((float)(8 + m), (int)e - 10) : ldexpf((float)m, -9);
    return (v & 0x80u) ? -mag : mag;
}
__device__ __forceinline__ unsigned gcn364_enc1(float f) {
    float a = fabsf(f);
    unsigned s = (__float_as_uint(f) >> 31) << 7;
    if (!(a > 0.f)) return s;
    if (a >= 448.f) return s | 0x7e;
    int ex; float fr = frexpf(a, &ex);   // a = fr*2^ex, fr in [0.5,1)
    int e = ex + 6;
    if (e <= 0) {
        unsigned m = (unsigned)(a * 512.f + 0.5f);
        if (m >= 8) return s | 0x08;
        return s | m;
    }
    unsigned m = (unsigned)(fr * 16.f - 8.f + 0.5f);
    if (m >= 8) { m = 0; e++; if (e > 15) return s | 0x7e; }
    return s | ((unsigned)e << 3) | m;
}
#endif

template<bool HI>
__device__ __forceinline__ gcn364_f2 gcn364_dec8(unsigned int u) {
#ifdef GCN364_HWFP8
    return __builtin_amdgcn_cvt_pk_f32_fp8((int)u, HI);
#else
    unsigned b = HI ? (u >> 16) : (u & 0xffffu);
    gcn364_f2 r;
    r.x = gcn364_dec1(b & 0xffu);
    r.y = gcn364_dec1((b >> 8) & 0xffu);
    return r;
#endif
}

template<bool HI>
__device__ __forceinline__ unsigned int gcn364_enc8(float f0, float f1, unsigned int old) {
#ifdef GCN364_HWFP8
    return (unsigned int)__builtin_amdgcn_cvt_pk_fp8_f32(f0, f1, (int)old, HI);
#else
    unsigned p = gcn364_enc1(f0) | (gcn364_enc1(f1) << 8);
    return HI ? ((old & 0x0000ffffu) | (p << 16)) : ((old & 0xffff0000u) | p);
#endif
}

// ---- dtype probe: flag=1 if x is fp32, flag=0 if bf16 ----
static __global__ void gcn364_detect(const unsigned short* __restrict__ xraw,
                                     int* __restrict__ flag) {
    __shared__ int cnt;
    if (threadIdx.x == 0) cnt = 0;
    __syncthreads();
    unsigned short u = xraw[threadIdx.x];
    int e = (u >> 7) & 0xFF;
    int outlier = (e < 100 || e > 140) ? 1 : 0;
    atomicAdd(&cnt, outlier);
    __syncthreads();
    if (threadIdx.x == 0) *flag = (cnt > 32) ? 1 : 0;
}

// ---- convert float inputs to fp32 region + int degree count (merged) ----
static __global__ void gcn364_convdeg(const void* __restrict__ x,
                                      const void* __restrict__ W1, const void* __restrict__ b1,
                                      const void* __restrict__ W2, const void* __restrict__ b2,
                                      const void* __restrict__ Wl, const void* __restrict__ bl,
                                      const int* __restrict__ flag,
                                      float* __restrict__ dstf,
                                      const int* __restrict__ edst, int* __restrict__ deg,
                                      int N, int E) {
    int i = blockIdx.x * blockDim.x + threadIdx.x;
    if (i < E) atomicAdd(&deg[edst[i]], 1);
    int total = DIN * N + NWEIGHT;
    if (i >= total) return;
    const void* srcp; int j = i;
    if (j < DIN * N) { srcp = x; }
    else {
        j -= DIN * N;
        if      (j < 384)                       { srcp = W1; }
        else if ((j -= 384)   < 128)            { srcp = b1; }
        else if ((j -= 128)   < 16384)          { srcp = W2; }
        else if ((j -= 16384) < 128)            { srcp = b2; }
        else if ((j -= 128)   < 1280)           { srcp = Wl; }
        else    { j -= 1280;                      srcp = bl; }
    }
    float v = (*flag) ? ((const float*)srcp)[j]
                      : gcn364_bf2f(((const unsigned short*)srcp)[j]);
    dstf[i] = v;
}

// ---- exclusive scan of deg[N] -> off[N], 1024 items/block ----
static __global__ void gcn364_scan1(const int* __restrict__ deg, int* __restrict__ off,
                                    int* __restrict__ partials, int N) {
    __shared__ int sh[256];
    int t = threadIdx.x;
    int base = blockIdx.x * 1024 + t * 4;
    int v0 = (base + 0 < N) ? deg[base + 0] : 0;
    int v1 = (base + 1 < N) ? deg[base + 1] : 0;
    int v2 = (base + 2 < N) ? deg[base + 2] : 0;
    int v3 = (base + 3 < N) ? deg[base + 3] : 0;
    int s = v0 + v1 + v2 + v3;
    sh[t] = s;
    __syncthreads();
    for (int d = 1; d < 256; d <<= 1) {
        int val = (t >= d) ? sh[t - d] : 0;
        __syncthreads();
        sh[t] += val;
        __syncthreads();
    }
    int excl = sh[t] - s;
    int run = excl;
    if (base + 0 < N) off[base + 0] = run; run += v0;
    if (base + 1 < N) off[base + 1] = run; run += v1;
    if (base + 2 < N) off[base + 2] = run; run += v2;
    if (base + 3 < N) off[base + 3] = run;
    if (t == 255) partials[blockIdx.x] = sh[255];
}

// block 0: scan of partials; block 1: nodes-per-graph via binary search
static __global__ void gcn364_scan2cnt(int* __restrict__ partials, int nb,
                                       const int* __restrict__ batch,
                                       float* __restrict__ cnt, int N, int G) {
    if (blockIdx.x == 0) {
        __shared__ int sh[256];
        int t = threadIdx.x;
        int v = (t < nb) ? partials[t] : 0;
        sh[t] = v;
        __syncthreads();
        for (int d = 1; d < 256; d <<= 1) {
            int val = (t >= d) ? sh[t - d] : 0;
            __syncthreads();
            sh[t] += val;
            __syncthreads();
        }
        if (t < nb) partials[t] = sh[t] - v;   // exclusive
    } else {
        for (int g = threadIdx.x; g < G; g += blockDim.x) {
            int lo = 0, hi = N;
            while (lo < hi) { int m = (lo + hi) >> 1; if (batch[m] < g) lo = m + 1; else hi = m; }
            int a = lo;
            lo = 0; hi = N;
            while (lo < hi) { int m = (lo + hi) >> 1; if (batch[m] < g + 1) lo = m + 1; else hi = m; }
            cnt[g] = (float)(lo - a);
        }
    }
}

// scan finalize + dinvs + in-place pre-scale of xf by dinvs
static __global__ void gcn364_scan3(int* __restrict__ off, const int* __restrict__ partials,
                                    const int* __restrict__ deg, float* __restrict__ dinvs,
                                    float* __restrict__ xf, int N) {
    int i = blockIdx.x * blockDim.x + threadIdx.x;
    if (i >= N) return;
    off[i] += partials[i >> 10];
    float di = rsqrtf((float)deg[i] + 1.0f);
    dinvs[i] = di;
    xf[i * DIN + 0] *= di;
    xf[i * DIN + 1] *= di;
    xf[i * DIN + 2] *= di;
}

// bucket fill: off[] doubles as cursor; afterwards off[i] == end offset of node i
static __global__ void gcn364_fill(const int* __restrict__ src, const int* __restrict__ dst,
                                   int* __restrict__ off, int* __restrict__ esrc, int E) {
    int e = blockIdx.x * blockDim.x + threadIdx.x;
    if (e >= E) return;
    int p = atomicAdd(&off[dst[e]], 1);
    esrc[p] = src[e];
}

// Fused layer-1 agg + GEMM + relu -> fp8 rows. 16 lanes per node, 4 nodes per
// wave. Lanes stripe the node's edge list (parallel scattered xf gather),
// shfl_xor reduce 3 sums, then each lane computes 8 features -> one 8B store.
// xf pre-scaled by dinvs; h1q = fp8(dinvs*relu(...)) (pre-scaled for layer 2).
static __global__ void gcn364_l1fused(const int* __restrict__ esrc,
                                      const int* __restrict__ endoff,
                                      const float* __restrict__ xf,
                                      const float* __restrict__ dinvs,
                                      const float* __restrict__ w1f,
                                      const float* __restrict__ b1f,
                                      uint2* __restrict__ h1q, int N) {
    int lane = threadIdx.x & 63;
    int wv = threadIdx.x >> 6;
    int grp = lane >> 4;
    int sub = lane & 15;
    int i = (blockIdx.x * 4 + wv) * 4 + grp;

    float a0 = 0.f, a1 = 0.f, a2 = 0.f;
    if (i < N) {
        int p0 = (i == 0) ? 0 : endoff[i - 1];
        int p1 = endoff[i];
        for (int p = p0 + sub; p < p1; p += 16) {
            int s = esrc[p];
            a0 += xf[s * DIN + 0];
            a1 += xf[s * DIN + 1];
            a2 += xf[s * DIN + 2];
        }
    }
    for (int d = 1; d < 16; d <<= 1) {
        a0 += __shfl_xor(a0, d);
        a1 += __shfl_xor(a1, d);
        a2 += __shfl_xor(a2, d);
    }
    if (i >= N) return;
    float di = dinvs[i];
    float v0 = di * (a0 + xf[i * DIN + 0]);
    float v1 = di * (a1 + xf[i * DIN + 1]);
    float v2 = di * (a2 + xf[i * DIN + 2]);

    float r[8];
    #pragma unroll
    for (int q = 0; q < 8; q++) {
        int f = sub * 8 + q;
        r[q] = di * fmaxf(v0 * w1f[f] + v1 * w1f[H + f] + v2 * w1f[2 * H + f] + b1f[f], 0.f);
    }
    unsigned int lo = 0, hi = 0;
    lo = gcn364_enc8<false>(r[0], r[1], lo);
    lo = gcn364_enc8<true >(r[2], r[3], lo);
    hi = gcn364_enc8<false>(r[4], r[5], hi);
    hi = gcn364_enc8<true >(r[6], r[7], hi);
    uint2 o; o.x = lo; o.y = hi;
    h1q[(size_t)i * 16 + sub] = o;
}

// Fused layer-2 CSR aggregation + GEMM + relu + mean-pool.
// Block = 256 thr = 4 waves; MPB=16 nodes/block. Phase A: each 16-lane group
// owns ONE node (4 nodes per wave in parallel) -> no reductions/shuffles.
// Rows are fp8 (128B): lane loads uint2, HW cvt_pk_f32_fp8 + packed adds.
// Phase B: 8-acc GEMM, float4 LDS reads, grouped atomics (batch sorted).
#define MPB 16
static __global__ void gcn364_agg2pool(const int* __restrict__ esrc,
                                       const int* __restrict__ endoff,
                                       const uint2* __restrict__ h1q,
                                       const float* __restrict__ dinvs,
                                       const float* __restrict__ w2f,
                                       const float* __restrict__ b2f,
                                       const int* __restrict__ batch,
                                       float* __restrict__ pooled, int N) {
    __shared__ float vsh[MPB][H];
    int i0 = blockIdx.x * MPB;
    int wave = threadIdx.x >> 6;
    int lane = threadIdx.x & 63;
    int grp = lane >> 4;
    int sub = lane & 15;
    int node = wave * 4 + grp;
    int i = i0 + node;

    gcn364_f2 a01 = {0.f, 0.f}, a23 = {0.f, 0.f}, a45 = {0.f, 0.f}, a67 = {0.f, 0.f};
    if (i < N) {
        int p0 = (i == 0) ? 0 : endoff[i - 1];
        int p1 = endoff[i];
        int p = p0;
        for (; p + 2 <= p1; p += 2) {
            int s0 = esrc[p];
            int s1 = esrc[p + 1];
            uint2 u0 = h1q[(size_t)s0 * 16 + sub];
            uint2 u1 = h1q[(size_t)s1 * 16 + sub];
            a01 += gcn364_dec8<false>(u0.x); a23 += gcn364_dec8<true>(u0.x);
            a45 += gcn364_dec8<false>(u0.y); a67 += gcn364_dec8<true>(u0.y);
            a01 += gcn364_dec8<false>(u1.x); a23 += gcn364_dec8<true>(u1.x);
            a45 += gcn364_dec8<false>(u1.y); a67 += gcn364_dec8<true>(u1.y);
        }
        if (p < p1) {
            int s0 = esrc[p];
            uint2 u0 = h1q[(size_t)s0 * 16 + sub];
            a01 += gcn364_dec8<false>(u0.x); a23 += gcn364_dec8<true>(u0.x);
            a45 += gcn364_dec8<false>(u0.y); a67 += gcn364_dec8<true>(u0.y);
        }
        {   // self-loop
            uint2 u0 = h1q[(size_t)i * 16 + sub];
            a01 += gcn364_dec8<false>(u0.x); a23 += gcn364_dec8<true>(u0.x);
            a45 += gcn364_dec8<false>(u0.y); a67 += gcn364_dec8<true>(u0.y);
        }
        float di = dinvs[i];
        a01 *= di; a23 *= di; a45 *= di; a67 *= di;
        *(float4*)&vsh[node][sub * 8 + 0] = make_float4(a01.x, a01.y, a23.x, a23.y);
        *(float4*)&vsh[node][sub * 8 + 4] = make_float4(a45.x, a45.y, a67.x, a67.y);
    }
    __syncthreads();

    int f = threadIdx.x & (H - 1);
    int half = threadIdx.x >> 7;
    float acc2[8] = {0.f, 0.f, 0.f, 0.f, 0.f, 0.f, 0.f, 0.f};
    for (int k4 = 0; k4 < H / 4; k4++) {
        float w0 = w2f[(k4 * 4 + 0) * H + f];
        float w1 = w2f[(k4 * 4 + 1) * H + f];
        float w2 = w2f[(k4 * 4 + 2) * H + f];
        float w3 = w2f[(k4 * 4 + 3) * H + f];
        #pragma unroll
        for (int n = 0; n < 8; n++) {
            float4 v = *(const float4*)&vsh[2 * n + half][k4 * 4];
            acc2[n] += v.x * w0 + v.y * w1 + v.z * w2 + v.w * w3;
        }
    }
    float bb = b2f[f];

    float sum = 0.0f;
    int curg = -1;
    #pragma unroll
    for (int j = 0; j < 8; j++) {
        int ii = i0 + half + 2 * j;
        if (ii >= N) continue;
        float val = fmaxf(acc2[j] + bb, 0.0f);
        int g = batch[ii];
        if (g != curg) {
            if (curg >= 0) atomicAdd(&pooled[curg * H + f], sum);
            curg = g;
            sum = 0.0f;
        }
        sum += val;
    }
    if (curg >= 0) atomicAdd(&pooled[curg * H + f], sum);
}

// out[g] = (pooled[g]/max(cnt,1)) @ Wl + bl  -> detected dtype
static __global__ void gcn364_final(const float* __restrict__ pooled,
                                    const float* __restrict__ cnt,
                                    const float* __restrict__ wlf,
                                    const float* __restrict__ blf,
                                    const int* __restrict__ flag,
                                    void* __restrict__ out, int G) {
    int g = blockIdx.x;
    int o = threadIdx.x;
    if (g >= G || o >= OUTF) return;
    float inv = 1.0f / fmaxf(cnt[g], 1.0f);
    float acc = 0.0f;
    for (int k = 0; k < H; k++)
        acc += pooled[g * H + k] * wlf[k * OUTF + o];
    float v = acc * inv + blf[o];
    if (*flag) ((float*)out)[g * OUTF + o] = v;
    else       ((unsigned short*)out)[g * OUTF + o] = gcn364_f2bf(v);
}

extern "C" void kernel_launch(void* const* d_in, const int* in_sizes, int n_in,
                              void* d_out, int out_size, void* d_ws, size_t ws_size,
                              hipStream_t stream) {
    const void* x  = d_in[0];
    const int* edge_index = (const int*)d_in[1];
    const int* batch      = (const int*)d_in[2];
    const void* W1 = d_in[3];
    const void* b1 = d_in[4];
    const void* W2 = d_in[5];
    const void* b2 = d_in[6];
    const void* Wl = d_in[7];
    const void* bl = d_in[8];

    const int N = in_sizes[0] / DIN;
    const int E = in_sizes[1] / 2;
    const int G = out_size / OUTF;
    const int* src = edge_index;
    const int* dst = edge_index + E;
    const int NB = (N + 1023) / 1024;   // scan blocks (must be <= 256)

    // ---- workspace layout (4B units); deg+pooled zeroed (contiguous) ----
    char* wsb = (char*)d_ws;
    int*   deg      = (int*)wsb;                                  // N      (zeroed)
    float* pooled   = (float*)(deg + N);                          // G*H    (zeroed)
    int*   off      = (int*)(pooled + (size_t)G * H);             // N
    int*   partials = off + N;                                    // 256
    float* cnt      = (float*)(partials + 256);                   // G
    float* dinvs    = cnt + G;                                    // N
    float* xf       = dinvs + N;                                  // 3N
    float* wf       = xf + (size_t)DIN * N;                       // NWEIGHT
    int*   flag     = (int*)(wf + NWEIGHT);                       // 1
    int*   esrc     = flag + 1;                                   // E
    size_t h1off = (((size_t)(esrc + E) - (size_t)wsb) + 15) & ~(size_t)15;
    uint2* h1q = (uint2*)(wsb + h1off);                           // N*16 uint2 (fp8 rows)

    float* w1f = wf;
    float* b1f = w1f + 384;
    float* w2f = b1f + 128;
    float* b2f = w2f + 16384;
    float* wlf = b2f + 128;
    float* blf = wlf + 1280;

    hipMemsetAsync(d_ws, 0, ((size_t)N + (size_t)G * H) * 4, stream);

    gcn364_detect<<<1, 256, 0, stream>>>((const unsigned short*)x, flag);
    {
        int total = DIN * N + NWEIGHT;
        int gmax = (E > total) ? E : total;
        gcn364_convdeg<<<(gmax + 255) / 256, 256, 0, stream>>>(
            x, W1, b1, W2, b2, Wl, bl, flag, xf, dst, deg, N, E);
    }
    gcn364_scan1<<<NB, 256, 0, stream>>>(deg, off, partials, N);
    gcn364_scan2cnt<<<2, 256, 0, stream>>>(partials, NB, batch, cnt, N, G);
    gcn364_scan3<<<(N + 255) / 256, 256, 0, stream>>>(off, partials, deg, dinvs, xf, N);
    gcn364_fill<<<(E + 255) / 256, 256, 0, stream>>>(src, dst, off, esrc, E);
    gcn364_l1fused<<<(N + 15) / 16, 256, 0, stream>>>(esrc, off, xf, dinvs, w1f, b1f, h1q, N);
    gcn364_agg2pool<<<(N + MPB - 1) / MPB, 256, 0, stream>>>(
        esrc, off, h1q, dinvs, w2f, b2f, batch, pooled, N);
    gcn364_final<<<G, 64, 0, stream>>>(pooled, cnt, wlf, blf, flag, d_out, G);
}

// Round 8
// 414.725 us; speedup vs baseline: 1.4561x; 1.0290x over previous
//
#include <hip/hip_runtime.h>

// GCN: 2x GCNConv(+self-loop sym-norm) + ReLU, global mean pool, linear head.
// N=100000, E=1600000, G=100, D_IN=3, H=128, OUT=10.
//
// R7->R8 key move: layer-1 output rows are a function of only 3 aggregated
// inputs, so agg2pool RECOMPUTES h1 rows per edge from a 16B/node u4 record
// (u0,u1,u2,di) with W1 columns held in registers, instead of gathering
// 128B fp8 rows from a 12.8MB (non-L2-resident) array. Gather working set
// 12.8MB -> 1.6MB (per-XCD L2 resident): agg2pool FETCH ~151MB -> ~0.
// fp8 machinery removed; layer-2 input is exact fp32 again.
//
// All kernels static + gcn364_ prefix (cross-.so symbol collisions caused the
// round-1 silent failure). Runtime dtype probe handles bf16/fp32 harness mode.

#define DIN 3
#define H 128
#define OUTF 10
#define NWEIGHT (384 + 128 + 16384 + 128 + 1280 + 10)  // W1,b1,W2,b2,Wl,bl

__device__ __forceinline__ float gcn364_bf2f(unsigned short u) {
    return __uint_as_float(((unsigned int)u) << 16);
}
__device__ __forceinline__ unsigned short gcn364_f2bf(float f) {
    unsigned int u = __float_as_uint(f);
    u += 0x7FFFu + ((u >> 16) & 1u);   // round-to-nearest-even
    return (unsigned short)(u >> 16);
}

// ---- dtype probe: flag=1 if x is fp32, flag=0 if bf16 ----
static __global__ void gcn364_detect(const unsigned short* __restrict__ xraw,
                                     int* __restrict__ flag) {
    __shared__ int cnt;
    if (threadIdx.x == 0) cnt = 0;
    __syncthreads();
    unsigned short u = xraw[threadIdx.x];
    int e = (u >> 7) & 0xFF;
    int outlier = (e < 100 || e > 140) ? 1 : 0;
    atomicAdd(&cnt, outlier);
    __syncthreads();
    if (threadIdx.x == 0) *flag = (cnt > 32) ? 1 : 0;
}

// ---- convert float inputs to fp32 region + int degree count (merged) ----
static __global__ void gcn364_convdeg(const void* __restrict__ x,
                                      const void* __restrict__ W1, const void* __restrict__ b1,
                                      const void* __restrict__ W2, const void* __restrict__ b2,
                                      const void* __restrict__ Wl, const void* __restrict__ bl,
                                      const int* __restrict__ flag,
                                      float* __restrict__ dstf,
                                      const int* __restrict__ edst, int* __restrict__ deg,
                                      int N, int E) {
    int i = blockIdx.x * blockDim.x + threadIdx.x;
    if (i < E) atomicAdd(&deg[edst[i]], 1);
    int total = DIN * N + NWEIGHT;
    if (i >= total) return;
    const void* srcp; int j = i;
    if (j < DIN * N) { srcp = x; }
    else {
        j -= DIN * N;
        if      (j < 384)                       { srcp = W1; }
        else if ((j -= 384)   < 128)            { srcp = b1; }
        else if ((j -= 128)   < 16384)          { srcp = W2; }
        else if ((j -= 16384) < 128)            { srcp = b2; }
        else if ((j -= 128)   < 1280)           { srcp = Wl; }
        else    { j -= 1280;                      srcp = bl; }
    }
    float v = (*flag) ? ((const float*)srcp)[j]
                      : gcn364_bf2f(((const unsigned short*)srcp)[j]);
    dstf[i] = v;
}

// ---- exclusive scan of deg[N] -> off[N], 1024 items/block ----
static __global__ void gcn364_scan1(const int* __restrict__ deg, int* __restrict__ off,
                                    int* __restrict__ partials, int N) {
    __shared__ int sh[256];
    int t = threadIdx.x;
    int base = blockIdx.x * 1024 + t * 4;
    int v0 = (base + 0 < N) ? deg[base + 0] : 0;
    int v1 = (base + 1 < N) ? deg[base + 1] : 0;
    int v2 = (base + 2 < N) ? deg[base + 2] : 0;
    int v3 = (base + 3 < N) ? deg[base + 3] : 0;
    int s = v0 + v1 + v2 + v3;
    sh[t] = s;
    __syncthreads();
    for (int d = 1; d < 256; d <<= 1) {
        int val = (t >= d) ? sh[t - d] : 0;
        __syncthreads();
        sh[t] += val;
        __syncthreads();
    }
    int excl = sh[t] - s;
    int run = excl;
    if (base + 0 < N) off[base + 0] = run; run += v0;
    if (base + 1 < N) off[base + 1] = run; run += v1;
    if (base + 2 < N) off[base + 2] = run; run += v2;
    if (base + 3 < N) off[base + 3] = run;
    if (t == 255) partials[blockIdx.x] = sh[255];
}

// block 0: scan of partials; block 1: nodes-per-graph via binary search
static __global__ void gcn364_scan2cnt(int* __restrict__ partials, int nb,
                                       const int* __restrict__ batch,
                                       float* __restrict__ cnt, int N, int G) {
    if (blockIdx.x == 0) {
        __shared__ int sh[256];
        int t = threadIdx.x;
        int v = (t < nb) ? partials[t] : 0;
        sh[t] = v;
        __syncthreads();
        for (int d = 1; d < 256; d <<= 1) {
            int val = (t >= d) ? sh[t - d] : 0;
            __syncthreads();
            sh[t] += val;
            __syncthreads();
        }
        if (t < nb) partials[t] = sh[t] - v;   // exclusive
    } else {
        for (int g = threadIdx.x; g < G; g += blockDim.x) {
            int lo = 0, hi = N;
            while (lo < hi) { int m = (lo + hi) >> 1; if (batch[m] < g) lo = m + 1; else hi = m; }
            int a = lo;
            lo = 0; hi = N;
            while (lo < hi) { int m = (lo + hi) >> 1; if (batch[m] < g + 1) lo = m + 1; else hi = m; }
            cnt[g] = (float)(lo - a);
        }
    }
}

// scan finalize + dinvs + in-place pre-scale of xf by dinvs
static __global__ void gcn364_scan3(int* __restrict__ off, const int* __restrict__ partials,
                                    const int* __restrict__ deg, float* __restrict__ dinvs,
                                    float* __restrict__ xf, int N) {
    int i = blockIdx.x * blockDim.x + threadIdx.x;
    if (i >= N) return;
    off[i] += partials[i >> 10];
    float di = rsqrtf((float)deg[i] + 1.0f);
    dinvs[i] = di;
    xf[i * DIN + 0] *= di;
    xf[i * DIN + 1] *= di;
    xf[i * DIN + 2] *= di;
}

// bucket fill: off[] doubles as cursor; afterwards off[i] == end offset of node i
static __global__ void gcn364_fill(const int* __restrict__ src, const int* __restrict__ dst,
                                   int* __restrict__ off, int* __restrict__ esrc, int E) {
    int e = blockIdx.x * blockDim.x + threadIdx.x;
    if (e >= E) return;
    int p = atomicAdd(&off[dst[e]], 1);
    esrc[p] = src[e];
}

// Layer-1 aggregation -> u4 records. 16 lanes per node, 4 nodes per wave.
// Lanes stripe the node's edge list (xf gathers are L2-resident: 1.2MB),
// shfl_xor reduce, lane 0 writes u4[i] = (di*(sum + xf[i]), di).
// xf pre-scaled by dinvs, so u = di*(Sum_s xf[s] + xf[i]) is the layer-1
// pre-GEMM input vector (agg + self-loop), and .w carries dinvs[i].
static __global__ void gcn364_aggu(const int* __restrict__ esrc,
                                   const int* __restrict__ endoff,
                                   const float* __restrict__ xf,
                                   const float* __restrict__ dinvs,
                                   float4* __restrict__ u4, int N) {
    int lane = threadIdx.x & 63;
    int wv = threadIdx.x >> 6;
    int grp = lane >> 4;
    int sub = lane & 15;
    int i = (blockIdx.x * 4 + wv) * 4 + grp;

    float a0 = 0.f, a1 = 0.f, a2 = 0.f;
    if (i < N) {
        int p0 = (i == 0) ? 0 : endoff[i - 1];
        int p1 = endoff[i];
        for (int p = p0 + sub; p < p1; p += 16) {
            int s = esrc[p];
            a0 += xf[s * DIN + 0];
            a1 += xf[s * DIN + 1];
            a2 += xf[s * DIN + 2];
        }
    }
    for (int d = 1; d < 16; d <<= 1) {
        a0 += __shfl_xor(a0, d);
        a1 += __shfl_xor(a1, d);
        a2 += __shfl_xor(a2, d);
    }
    if (i < N && sub == 0) {
        float di = dinvs[i];
        u4[i] = make_float4(di * (a0 + xf[i * DIN + 0]),
                            di * (a1 + xf[i * DIN + 1]),
                            di * (a2 + xf[i * DIN + 2]), di);
    }
}

// Fused layer-2: per-edge ON-THE-FLY layer-1 row recompute + aggregation +
// GEMM + relu + mean-pool. Block = 256 thr = 4 waves; MPB=16 nodes/block.
// Phase A: each 16-lane group owns one node; per edge it loads u4[s] (16B,
// L2-resident 1.6MB, same-address broadcast across the group) and computes
// its 8 features: h1s_f = u.w * relu(u.xyz @ W1[:,f] + b1[f]) with W1 columns
// in registers (loaded once). Accumulate, add self-loop term, scale by di.
// Phase B: 8-acc GEMM over W2, float4 LDS reads, grouped atomics (batch
// sorted).
#define MPB 16
static __global__ void gcn364_agg2pool(const int* __restrict__ esrc,
                                       const int* __restrict__ endoff,
                                       const float4* __restrict__ u4,
                                       const float* __restrict__ w1f,
                                       const float* __restrict__ b1f,
                                       const float* __restrict__ w2f,
                                       const float* __restrict__ b2f,
                                       const int* __restrict__ batch,
                                       float* __restrict__ pooled, int N) {
    __shared__ float vsh[MPB][H];
    int i0 = blockIdx.x * MPB;
    int wave = threadIdx.x >> 6;
    int lane = threadIdx.x & 63;
    int grp = lane >> 4;
    int sub = lane & 15;
    int node = wave * 4 + grp;
    int i = i0 + node;

    // W1 columns for this lane's 8 features (once per kernel)
    float wa[8], wb[8], wc[8], bb1[8];
    #pragma unroll
    for (int q = 0; q < 8; q++) {
        int f = sub * 8 + q;
        wa[q] = w1f[f];
        wb[q] = w1f[H + f];
        wc[q] = w1f[2 * H + f];
        bb1[q] = b1f[f];
    }

    float acc[8] = {0.f, 0.f, 0.f, 0.f, 0.f, 0.f, 0.f, 0.f};
    if (i < N) {
        int p0 = (i == 0) ? 0 : endoff[i - 1];
        int p1 = endoff[i];
        int p = p0;
        for (; p + 2 <= p1; p += 2) {
            int s0 = esrc[p];
            int s1 = esrc[p + 1];
            float4 uA = u4[s0];
            float4 uB = u4[s1];
            #pragma unroll
            for (int q = 0; q < 8; q++) {
                float t = fmaf(uA.x, wa[q], fmaf(uA.y, wb[q], fmaf(uA.z, wc[q], bb1[q])));
                acc[q] = fmaf(uA.w, fmaxf(t, 0.f), acc[q]);
            }
            #pragma unroll
            for (int q = 0; q < 8; q++) {
                float t = fmaf(uB.x, wa[q], fmaf(uB.y, wb[q], fmaf(uB.z, wc[q], bb1[q])));
                acc[q] = fmaf(uB.w, fmaxf(t, 0.f), acc[q]);
            }
        }
        if (p < p1) {
            float4 uA = u4[esrc[p]];
            #pragma unroll
            for (int q = 0; q < 8; q++) {
                float t = fmaf(uA.x, wa[q], fmaf(uA.y, wb[q], fmaf(uA.z, wc[q], bb1[q])));
                acc[q] = fmaf(uA.w, fmaxf(t, 0.f), acc[q]);
            }
        }
        float4 uS = u4[i];   // self-loop
        #pragma unroll
        for (int q = 0; q < 8; q++) {
            float t = fmaf(uS.x, wa[q], fmaf(uS.y, wb[q], fmaf(uS.z, wc[q], bb1[q])));
            acc[q] = fmaf(uS.w, fmaxf(t, 0.f), acc[q]);
        }
        float di = uS.w;
        *(float4*)&vsh[node][sub * 8 + 0] =
            make_float4(acc[0] * di, acc[1] * di, acc[2] * di, acc[3] * di);
        *(float4*)&vsh[node][sub * 8 + 4] =
            make_float4(acc[4] * di, acc[5] * di, acc[6] * di, acc[7] * di);
    }
    __syncthreads();

    int f = threadIdx.x & (H - 1);
    int half = threadIdx.x >> 7;
    float acc2[8] = {0.f, 0.f, 0.f, 0.f, 0.f, 0.f, 0.f, 0.f};
    for (int k4 = 0; k4 < H / 4; k4++) {
        float w0 = w2f[(k4 * 4 + 0) * H + f];
        float w1 = w2f[(k4 * 4 + 1) * H + f];
        float w2 = w2f[(k4 * 4 + 2) * H + f];
        float w3 = w2f[(k4 * 4 + 3) * H + f];
        #pragma unroll
        for (int n = 0; n < 8; n++) {
            float4 v = *(const float4*)&vsh[2 * n + half][k4 * 4];
            acc2[n] += v.x * w0 + v.y * w1 + v.z * w2 + v.w * w3;
        }
    }
    float bb = b2f[f];

    float sum = 0.0f;
    int curg = -1;
    #pragma unroll
    for (int j = 0; j < 8; j++) {
        int ii = i0 + half + 2 * j;
        if (ii >= N) continue;
        float val = fmaxf(acc2[j] + bb, 0.0f);
        int g = batch[ii];
        if (g != curg) {
            if (curg >= 0) atomicAdd(&pooled[curg * H + f], sum);
            curg = g;
            sum = 0.0f;
        }
        sum += val;
    }
    if (curg >= 0) atomicAdd(&pooled[curg * H + f], sum);
}

// out[g] = (pooled[g]/max(cnt,1)) @ Wl + bl  -> detected dtype
static __global__ void gcn364_final(const float* __restrict__ pooled,
                                    const float* __restrict__ cnt,
                                    const float* __restrict__ wlf,
                                    const float* __restrict__ blf,
                                    const int* __restrict__ flag,
                                    void* __restrict__ out, int G) {
    int g = blockIdx.x;
    int o = threadIdx.x;
    if (g >= G || o >= OUTF) return;
    float inv = 1.0f / fmaxf(cnt[g], 1.0f);
    float acc = 0.0f;
    for (int k = 0; k < H; k++)
        acc += pooled[g * H + k] * wlf[k * OUTF + o];
    float v = acc * inv + blf[o];
    if (*flag) ((float*)out)[g * OUTF + o] = v;
    else       ((unsigned short*)out)[g * OUTF + o] = gcn364_f2bf(v);
}

extern "C" void kernel_launch(void* const* d_in, const int* in_sizes, int n_in,
                              void* d_out, int out_size, void* d_ws, size_t ws_size,
                              hipStream_t stream) {
    const void* x  = d_in[0];
    const int* edge_index = (const int*)d_in[1];
    const int* batch      = (const int*)d_in[2];
    const void* W1 = d_in[3];
    const void* b1 = d_in[4];
    const void* W2 = d_in[5];
    const void* b2 = d_in[6];
    const void* Wl = d_in[7];
    const void* bl = d_in[8];

    const int N = in_sizes[0] / DIN;
    const int E = in_sizes[1] / 2;
    const int G = out_size / OUTF;
    const int* src = edge_index;
    const int* dst = edge_index + E;
    const int NB = (N + 1023) / 1024;   // scan blocks (must be <= 256)

    // ---- workspace layout (4B units); deg+pooled zeroed (contiguous) ----
    char* wsb = (char*)d_ws;
    int*   deg      = (int*)wsb;                                  // N      (zeroed)
    float* pooled   = (float*)(deg + N);                          // G*H    (zeroed)
    int*   off      = (int*)(pooled + (size_t)G * H);             // N
    int*   partials = off + N;                                    // 256
    float* cnt      = (float*)(partials + 256);                   // G
    float* dinvs    = cnt + G;                                    // N
    float* xf       = dinvs + N;                                  // 3N
    float* wf       = xf + (size_t)DIN * N;                       // NWEIGHT
    int*   flag     = (int*)(wf + NWEIGHT);                       // 1
    int*   esrc     = flag + 1;                                   // E
    size_t u4off = (((size_t)(esrc + E) - (size_t)wsb) + 15) & ~(size_t)15;
    float4* u4 = (float4*)(wsb + u4off);                          // N float4

    float* w1f = wf;
    float* b1f = w1f + 384;
    float* w2f = b1f + 128;
    float* b2f = w2f + 16384;
    float* wlf = b2f + 128;
    float* blf = wlf + 1280;

    hipMemsetAsync(d_ws, 0, ((size_t)N + (size_t)G * H) * 4, stream);

    gcn364_detect<<<1, 256, 0, stream>>>((const unsigned short*)x, flag);
    {
        int total = DIN * N + NWEIGHT;
        int gmax = (E > total) ? E : total;
        gcn364_convdeg<<<(gmax + 255) / 256, 256, 0, stream>>>(
            x, W1, b1, W2, b2, Wl, bl, flag, xf, dst, deg, N, E);
    }
    gcn364_scan1<<<NB, 256, 0, stream>>>(deg, off, partials, N);
    gcn364_scan2cnt<<<2, 256, 0, stream>>>(partials, NB, batch, cnt, N, G);
    gcn364_scan3<<<(N + 255) / 256, 256, 0, stream>>>(off, partials, deg, dinvs, xf, N);
    gcn364_fill<<<(E + 255) / 256, 256, 0, stream>>>(src, dst, off, esrc, E);
    gcn364_aggu<<<(N + 15) / 16, 256, 0, stream>>>(esrc, off, xf, dinvs, u4, N);
    gcn364_agg2pool<<<(N + MPB - 1) / MPB, 256, 0, stream>>>(
        esrc, off, u4, w1f, b1f, w2f, b2f, batch, pooled, N);
    gcn364_final<<<G, 64, 0, stream>>>(pooled, cnt, wlf, blf, flag, d_out, G);
}